// Round 6
// baseline (98.907 us; speedup 1.0000x reference)
//
#include <hip/hip_runtime.h>
#include <hip/hip_bf16.h>
#include <cmath>

#define PHI_F   1.6180339887498949f
#define INV2PI  0.15915494309189535f
#define SQRT2F  1.41421356237309505f
#define TLASTF  (63.0f * 1.6180339887498949f)
#define LOG2EF  1.4426950408889634f

typedef __attribute__((ext_vector_type(8))) short bf16x8;
typedef __attribute__((ext_vector_type(4))) float f32x4;

__device__ __forceinline__ unsigned short bf16rn(float x) {
    const unsigned u = __float_as_uint(x);
    return (unsigned short)((u + 0x7fffu + ((u >> 16) & 1u)) >> 16);
}

// 8x fp32 -> bf16x8 (RN-even), inline weight conversion
__device__ __forceinline__ bf16x8 cvt8(float4 a, float4 b) {
    union { bf16x8 v; __hip_bfloat162 h2[4]; } u;
    u.h2[0] = __float22bfloat162_rn(make_float2(a.x, a.y));
    u.h2[1] = __float22bfloat162_rn(make_float2(a.z, a.w));
    u.h2[2] = __float22bfloat162_rn(make_float2(b.x, b.y));
    u.h2[3] = __float22bfloat162_rn(make_float2(b.z, b.w));
    return u.v;
}

// Grid barrier, r4-postmortem-fixed:
//   arrive  = RMW with RELEASE (one wbL2 per block, folded into the atomic)
//   poll    = RELAXED atomic load (global_load sc1 — reads coherence point,
//             does NOT invalidate L2; r4's per-poll acquire was the death spiral)
//   depart  = ONE acquire load (single buffer_inv per block)
__device__ __forceinline__ void gridbar(unsigned* cnt) {
    __syncthreads();
    if (threadIdx.x == 0) {
        __hip_atomic_fetch_add(cnt, 1u, __ATOMIC_RELEASE, __HIP_MEMORY_SCOPE_AGENT);
        while (__hip_atomic_load(cnt, __ATOMIC_RELAXED, __HIP_MEMORY_SCOPE_AGENT) < 256u)
            __builtin_amdgcn_s_sleep(16);
        (void)__hip_atomic_load(cnt, __ATOMIC_ACQUIRE, __HIP_MEMORY_SCOPE_AGENT);
    }
    __syncthreads();
}

// 16x16 NT fragment: A = bf16 activations (hi only), B = fp32 weights cvt'd
// inline. 3 x 16B loads + 1 MFMA per 32-wide k-step, fully unrolled.
// C/D: col = lane&15, row = 4*(lane>>4) + reg
template<int KC>
__device__ __forceinline__ f32x4 frag1(
    const unsigned short* __restrict__ Ah, const float* __restrict__ B,
    int lda, int ldb, int m0, int n0, int k0, int lane)
{
    const int rr = lane & 15;
    const int ko = (lane >> 4) * 8;
    const unsigned short* ap = Ah + (size_t)(m0 + rr) * lda + k0 + ko;
    const float*          bp = B  + (size_t)(n0 + rr) * ldb + k0 + ko;
    f32x4 acc = {0.f, 0.f, 0.f, 0.f};
    #pragma unroll
    for (int kk = 0; kk < KC; kk += 32) {
        const bf16x8 ah = *(const bf16x8*)(ap + kk);
        const float4 b0 = *(const float4*)(bp + kk);
        const float4 b1 = *(const float4*)(bp + kk + 4);
        acc = __builtin_amdgcn_mfma_f32_16x16x32_bf16(ah, cvt8(b0, b1), acc, 0, 0, 0);
    }
    return acc;
}

// ---------------------------------------------------------------------------
// Persistent kernel: 256 blocks x 512 threads (8 waves, 1+ block/CU).
// rec | th0 | pv0 | th1 | pv1 | logits, 5 fixed barriers.
// Weights are read fp32 DIRECTLY from inputs in exactly one phase each, so
// barrier L2 invalidation causes no weight refetch (r4's 36MB bug).
// ---------------------------------------------------------------------------
__global__ __launch_bounds__(512) void mega(
    const int* __restrict__ ids, const float* __restrict__ te,
    const float* __restrict__ W, const float* __restrict__ bias,
    const float* __restrict__ Pr, const float* __restrict__ Pi,
    const float* __restrict__ op, float* __restrict__ out,
    unsigned* __restrict__ cnt, float* __restrict__ h,
    unsigned short* __restrict__ hh,
    unsigned short* __restrict__ ct, unsigned short* __restrict__ st)
{
    __shared__ float red[8][260];
    __shared__ int sid[64];
    const int tid = threadIdx.x, bid = blockIdx.x;
    const int lane = tid & 63, w = tid >> 6;

    // ---------------- P0: rotation recurrence (blocks 0..127) -------------
    if (bid < 128) {
        if (tid < 64) sid[tid] = ids[bid * 64 + tid];
        __syncthreads();
        const int d = tid;  // 0..511
        float wv[2][8], bev[2][8];
        #pragma unroll
        for (int j = 0; j < 8; ++j) {
            const int id = sid[j];
            wv[0][j]  = te[id * 1024 + d];
            bev[0][j] = te[id * 1024 + 512 + d];
        }
        float v = 0.f;
        #pragma unroll
        for (int g = 0; g < 8; ++g) {
            const int cur = g & 1, nxt = cur ^ 1;
            if (g < 7) {
                #pragma unroll
                for (int j = 0; j < 8; ++j) {
                    const int id = sid[(g + 1) * 8 + j];
                    wv[nxt][j]  = te[id * 1024 + d];
                    bev[nxt][j] = te[id * 1024 + 512 + d];
                }
            }
            #pragma unroll
            for (int j = 0; j < 8; ++j) {
                const int t = g * 8 + j;
                const float rlam = __builtin_amdgcn_rcpf(1.0f + fabsf(wv[cur][j]));
                const float a2 = (SQRT2F * INV2PI) * rlam;
                const float b2 = fmaf(2.0f * INV2PI, bev[cur][j],
                                      fmaf((float)t, 2.0f * PHI_F * INV2PI, 0.125f));
                v = __builtin_amdgcn_sinf(__builtin_amdgcn_fractf(fmaf(v, a2, b2)));
            }
        }
        const float u = SQRT2F * v;
        h[bid * 512 + d] = u;
        hh[bid * 512 + d] = bf16rn(u);
    }
    gridbar(cnt + 0);

    // ---------------- layers ----------------
    #pragma unroll 1
    for (int l = 0; l < 2; ++l) {
        // ---- theta: M=128,N=1024,K=512; 2 tiles/block x 4-way split-K ----
        {
            const float* Wl = W + (size_t)l * 524288;
            const int tile = bid * 2 + (w >> 2);
            const int mt = tile >> 6, nt = tile & 63;
            const f32x4 acc = frag1<128>(hh, Wl, 512, 512,
                                         mt * 16, nt * 16, (w & 3) * 128, lane);
            *(f32x4*)&red[w][lane * 4] = acc;
            __syncthreads();
            if ((w & 3) < 2) {
                const int grp = (w >> 2) * 4;
                float4 s = {0.f, 0.f, 0.f, 0.f};
                #pragma unroll
                for (int ww = 0; ww < 4; ++ww) {
                    const float4 q = *(const float4*)&red[grp + ww][lane * 4];
                    s.x += q.x; s.y += q.y; s.z += q.z; s.w += q.w;
                }
                const int sel = w & 3;  // 0 -> cos, 1 -> sin
                unsigned short* dst = sel ? st : ct;
                const int col = lane & 15, rb = (lane >> 4) * 4;
                const int n = nt * 16 + col;
                const float bn = bias[l * 1024 + n] + TLASTF;
                const float sv[4] = {s.x, s.y, s.z, s.w};
                #pragma unroll
                for (int r = 0; r < 4; ++r) {
                    const int m = mt * 16 + rb + r;
                    const float fr = __builtin_amdgcn_fractf((sv[r] + bn) * INV2PI);
                    const float vv = sel ? __builtin_amdgcn_sinf(fr)
                                         : __builtin_amdgcn_cosf(fr);
                    dst[m * 1024 + n] = bf16rn(vv);
                }
            }
        }
        gridbar(cnt + (1 + 2 * l) * 16);

        // ---- pv: h += silu(ct@Pr^T + st@Pi^T); M=128,N=512,K=1024x2 ----
        {
            const int mt = bid >> 5, nt = bid & 31;
            const int p = w >> 2, k0 = (w & 3) * 256;
            const unsigned short* A = p ? st : ct;
            const float* B = (p ? Pi : Pr) + (size_t)l * 524288;
            const f32x4 acc = frag1<256>(A, B, 1024, 1024,
                                         mt * 16, nt * 16, k0, lane);
            *(f32x4*)&red[w][lane * 4] = acc;
            __syncthreads();
            if (w == 0) {
                float4 s = {0.f, 0.f, 0.f, 0.f};
                #pragma unroll
                for (int ww = 0; ww < 8; ++ww) {
                    const float4 q = *(const float4*)&red[ww][lane * 4];
                    s.x += q.x; s.y += q.y; s.z += q.z; s.w += q.w;
                }
                const int col = lane & 15, rb = (lane >> 4) * 4;
                const int dn = nt * 16 + col;
                const float sv[4] = {s.x, s.y, s.z, s.w};
                #pragma unroll
                for (int r = 0; r < 4; ++r) {
                    const int m = mt * 16 + rb + r;
                    const float x = sv[r];
                    const float sig = __builtin_amdgcn_rcpf(
                        1.0f + __builtin_amdgcn_exp2f(-LOG2EF * x));
                    const float val = h[m * 512 + dn] + x * sig;
                    h[m * 512 + dn] = val;
                    hh[m * 512 + dn] = bf16rn(val);
                }
            }
        }
        gridbar(cnt + (2 + 2 * l) * 16);
    }

    // ---------------- logits: M=128,N=1024,K=512; 2 tiles/block ----------
    {
        const int tile = bid * 2 + (w >> 2);
        const int mt = tile >> 6, nt = tile & 63;
        const f32x4 acc = frag1<128>(hh, op, 512, 512,
                                     mt * 16, nt * 16, (w & 3) * 128, lane);
        *(f32x4*)&red[w][lane * 4] = acc;
        __syncthreads();
        if ((w & 3) == 0) {
            const int grp = (w >> 2) * 4;
            float4 s = {0.f, 0.f, 0.f, 0.f};
            #pragma unroll
            for (int ww = 0; ww < 4; ++ww) {
                const float4 q = *(const float4*)&red[grp + ww][lane * 4];
                s.x += q.x; s.y += q.y; s.z += q.z; s.w += q.w;
            }
            const int col = lane & 15, rb = (lane >> 4) * 4;
            const int n = nt * 16 + col;
            const float sv[4] = {s.x, s.y, s.z, s.w};
            #pragma unroll
            for (int r = 0; r < 4; ++r)
                out[(size_t)(mt * 16 + rb + r) * 1024 + n] = sv[r];
        }
    }
}

// ---------------------------------------------------------------------------
// B=128, S=64, V=1024, D=512, N=1024, L=2
// ws: cnt 5x64B | h 65,536 f32 | hh 65,536 us | ct/st 131,072 us  (~0.9 MiB)
// ---------------------------------------------------------------------------
extern "C" void kernel_launch(void* const* d_in, const int* in_sizes, int n_in,
                              void* d_out, int out_size, void* d_ws, size_t ws_size,
                              hipStream_t stream) {
    const int*   ids   = (const int*)d_in[0];
    const float* te    = (const float*)d_in[1];
    const float* W     = (const float*)d_in[2];
    const float* bias  = (const float*)d_in[3];
    const float* Pr    = (const float*)d_in[4];
    const float* Pi    = (const float*)d_in[5];
    const float* oproj = (const float*)d_in[6];
    float* out = (float*)d_out;

    unsigned*       cnt = (unsigned*)d_ws;               // 5 counters, 64B apart
    float*          h   = (float*)((char*)d_ws + 512);   // 65,536 f32
    unsigned short* hh  = (unsigned short*)(h + 65536);  // 65,536
    unsigned short* ct  = hh + 65536;                    // 131,072
    unsigned short* st  = ct + 131072;                   // 131,072

    hipMemsetAsync(d_ws, 0, 512, stream);  // zero barrier counters
    mega<<<256, 512, 0, stream>>>(ids, te, W, bias, Pr, Pi, oproj, out,
                                  cnt, h, hh, ct, st);
}

// Round 7
// 42.305 us; speedup vs baseline: 2.3379x; 2.3379x over previous
//
#include <hip/hip_runtime.h>
#include <hip/hip_bf16.h>
#include <cmath>

#define PHI_F   1.6180339887498949f
#define INV2PI  0.15915494309189535f
#define SQRT2F  1.41421356237309505f
#define TLASTF  (63.0f * 1.6180339887498949f)
#define LOG2EF  1.4426950408889634f

typedef __attribute__((ext_vector_type(8))) short bf16x8;
typedef __attribute__((ext_vector_type(4))) float f32x4;

__device__ __forceinline__ unsigned short bf16rn(float x) {
    const unsigned u = __float_as_uint(x);
    return (unsigned short)((u + 0x7fffu + ((u >> 16) & 1u)) >> 16);
}

// 8x fp32 -> bf16x8 (RN-even), inline weight conversion
__device__ __forceinline__ bf16x8 cvt8(float4 a, float4 b) {
    union { bf16x8 v; __hip_bfloat162 h2[4]; } u;
    u.h2[0] = __float22bfloat162_rn(make_float2(a.x, a.y));
    u.h2[1] = __float22bfloat162_rn(make_float2(a.z, a.w));
    u.h2[2] = __float22bfloat162_rn(make_float2(b.x, b.y));
    u.h2[3] = __float22bfloat162_rn(make_float2(b.z, b.w));
    return u.v;
}

// ---------------------------------------------------------------------------
// Recurrence: 256 blocks x 256 thr (b = bid>>1, d = (bid&1)*256+tid).
// Depth-8 register prefetch hides te-gather latency under the serial sin chain.
// ---------------------------------------------------------------------------
__global__ __launch_bounds__(256) void rinrec_k(
    const int* __restrict__ ids, const float* __restrict__ te,
    float* __restrict__ h, unsigned short* __restrict__ hh)
{
    const int b = blockIdx.x >> 1;
    const int d = ((blockIdx.x & 1) << 8) + threadIdx.x;
    __shared__ int sid[64];
    if (threadIdx.x < 64) sid[threadIdx.x] = ids[b * 64 + threadIdx.x];
    __syncthreads();

    float wv[2][8], bev[2][8];
    #pragma unroll
    for (int j = 0; j < 8; ++j) {
        const int id = sid[j];
        wv[0][j]  = te[id * 1024 + d];
        bev[0][j] = te[id * 1024 + 512 + d];
    }
    float v = 0.f;
    #pragma unroll
    for (int g = 0; g < 8; ++g) {
        const int cur = g & 1, nxt = cur ^ 1;
        if (g < 7) {
            #pragma unroll
            for (int j = 0; j < 8; ++j) {
                const int id = sid[(g + 1) * 8 + j];
                wv[nxt][j]  = te[id * 1024 + d];
                bev[nxt][j] = te[id * 1024 + 512 + d];
            }
        }
        #pragma unroll
        for (int j = 0; j < 8; ++j) {
            const int t = g * 8 + j;
            const float rlam = __builtin_amdgcn_rcpf(1.0f + fabsf(wv[cur][j]));
            const float a2 = (SQRT2F * INV2PI) * rlam;
            const float b2 = fmaf(2.0f * INV2PI, bev[cur][j],
                                  fmaf((float)t, 2.0f * PHI_F * INV2PI, 0.125f));
            v = __builtin_amdgcn_sinf(__builtin_amdgcn_fractf(fmaf(v, a2, b2)));
        }
    }
    const float u = SQRT2F * v;
    h[b * 512 + d] = u;
    hh[b * 512 + d] = bf16rn(u);
}

// ---------------------------------------------------------------------------
// 16x16 NT fragment: A = bf16 activations, B = fp32 weights cvt'd inline.
// 3 x 16B loads + 1 MFMA per 32-wide k-step, fully unrolled (KC/32 iters).
// C/D: col = lane&15, row = 4*(lane>>4) + reg
// ---------------------------------------------------------------------------
template<int KC>
__device__ __forceinline__ f32x4 frag1(
    const unsigned short* __restrict__ Ah, const float* __restrict__ B,
    int lda, int ldb, int m0, int n0, int k0, int lane)
{
    const int rr = lane & 15;
    const int ko = (lane >> 4) * 8;
    const unsigned short* ap = Ah + (size_t)(m0 + rr) * lda + k0 + ko;
    const float*          bp = B  + (size_t)(n0 + rr) * ldb + k0 + ko;
    f32x4 acc = {0.f, 0.f, 0.f, 0.f};
    #pragma unroll
    for (int kk = 0; kk < KC; kk += 32) {
        const bf16x8 ah = *(const bf16x8*)(ap + kk);
        const float4 b0 = *(const float4*)(bp + kk);
        const float4 b1 = *(const float4*)(bp + kk + 4);
        acc = __builtin_amdgcn_mfma_f32_16x16x32_bf16(ah, cvt8(b0, b1), acc, 0, 0, 0);
    }
    return acc;
}

// ---------------------------------------------------------------------------
// theta: ct/st = cos/sin(h @ W^T + bias + t_last), bf16.
// M=128,N=1024,K=512. 512 blocks (1 tile: mt=bid>>6, nt=bid&63) x 8 waves
// (split-K KC=64) -> 16 waves/CU.
// ---------------------------------------------------------------------------
__global__ __launch_bounds__(512) void theta_k(
    const unsigned short* __restrict__ hh,
    const float* __restrict__ W, const float* __restrict__ bias,
    unsigned short* __restrict__ ct, unsigned short* __restrict__ st)
{
    __shared__ float red[8][260];
    const int lane = threadIdx.x & 63;
    const int w = threadIdx.x >> 6;
    const int nt = blockIdx.x & 63, mt = blockIdx.x >> 6;
    const f32x4 acc = frag1<64>(hh, W, 512, 512,
                                mt * 16, nt * 16, w * 64, lane);
    *(f32x4*)&red[w][lane * 4] = acc;
    __syncthreads();
    if (w < 2) {
        float4 s = {0.f, 0.f, 0.f, 0.f};
        #pragma unroll
        for (int ww = 0; ww < 8; ++ww) {
            const float4 q = *(const float4*)&red[ww][lane * 4];
            s.x += q.x; s.y += q.y; s.z += q.z; s.w += q.w;
        }
        unsigned short* dst = w ? st : ct;
        const int col = lane & 15, rb = (lane >> 4) * 4;
        const int n = nt * 16 + col;
        const float bn = bias[n] + TLASTF;
        const float sv[4] = {s.x, s.y, s.z, s.w};
        #pragma unroll
        for (int r = 0; r < 4; ++r) {
            const int m = mt * 16 + rb + r;
            const float fr = __builtin_amdgcn_fractf((sv[r] + bn) * INV2PI);
            const float vv = w ? __builtin_amdgcn_sinf(fr)
                               : __builtin_amdgcn_cosf(fr);
            dst[m * 1024 + n] = bf16rn(vv);
        }
    }
}

// ---------------------------------------------------------------------------
// pv: h += silu(ct @ Pr^T + st @ Pi^T); h rewritten fp32 + bf16.
// M=128,N=512,K=1024 per pair. 256 blocks (mt=bid>>5, nt=bid&31) x 16 waves
// (pair = w>>3, k-chunk KC=128) -> 16 waves/CU.
// ---------------------------------------------------------------------------
__global__ __launch_bounds__(1024) void pv_k(
    const unsigned short* __restrict__ ct, const unsigned short* __restrict__ st,
    const float* __restrict__ Pr, const float* __restrict__ Pi,
    float* __restrict__ h, unsigned short* __restrict__ hh)
{
    __shared__ float red[16][260];
    const int lane = threadIdx.x & 63;
    const int w = threadIdx.x >> 6;
    const int nt = blockIdx.x & 31, mt = blockIdx.x >> 5;
    const int p = w >> 3, k0 = (w & 7) * 128;
    const unsigned short* A = p ? st : ct;
    const float* B = p ? Pi : Pr;
    const f32x4 acc = frag1<128>(A, B, 1024, 1024,
                                 mt * 16, nt * 16, k0, lane);
    *(f32x4*)&red[w][lane * 4] = acc;
    __syncthreads();
    if (w == 0) {
        float4 s = {0.f, 0.f, 0.f, 0.f};
        #pragma unroll
        for (int ww = 0; ww < 16; ++ww) {
            const float4 q = *(const float4*)&red[ww][lane * 4];
            s.x += q.x; s.y += q.y; s.z += q.z; s.w += q.w;
        }
        const int col = lane & 15, rb = (lane >> 4) * 4;
        const int dn = nt * 16 + col;
        const float sv[4] = {s.x, s.y, s.z, s.w};
        #pragma unroll
        for (int r = 0; r < 4; ++r) {
            const int m = mt * 16 + rb + r;
            const float x = sv[r];
            const float sig = __builtin_amdgcn_rcpf(
                1.0f + __builtin_amdgcn_exp2f(-LOG2EF * x));
            const float val = h[m * 512 + dn] + x * sig;
            h[m * 512 + dn] = val;
            hh[m * 512 + dn] = bf16rn(val);
        }
    }
}

// ---------------------------------------------------------------------------
// logits = h @ oproj^T  (M=128,N=1024,K=512). 512 blocks x 8 waves (KC=64).
// ---------------------------------------------------------------------------
__global__ __launch_bounds__(512) void logits_k(
    const unsigned short* __restrict__ hh,
    const float* __restrict__ op, float* __restrict__ out)
{
    __shared__ float red[8][260];
    const int lane = threadIdx.x & 63;
    const int w = threadIdx.x >> 6;
    const int nt = blockIdx.x & 63, mt = blockIdx.x >> 6;
    const f32x4 acc = frag1<64>(hh, op, 512, 512,
                                mt * 16, nt * 16, w * 64, lane);
    *(f32x4*)&red[w][lane * 4] = acc;
    __syncthreads();
    if (w == 0) {
        float4 s = {0.f, 0.f, 0.f, 0.f};
        #pragma unroll
        for (int ww = 0; ww < 8; ++ww) {
            const float4 q = *(const float4*)&red[ww][lane * 4];
            s.x += q.x; s.y += q.y; s.z += q.z; s.w += q.w;
        }
        const int col = lane & 15, rb = (lane >> 4) * 4;
        const int n = nt * 16 + col;
        const float sv[4] = {s.x, s.y, s.z, s.w};
        #pragma unroll
        for (int r = 0; r < 4; ++r)
            out[(size_t)(mt * 16 + rb + r) * 1024 + n] = sv[r];
    }
}

// ---------------------------------------------------------------------------
// B=128, S=64, V=1024, D=512, N=1024, L=2
// ws: h 65,536 f32 | hh 65,536 us | ct/st 131,072 us  (~0.9 MiB)
// ---------------------------------------------------------------------------
extern "C" void kernel_launch(void* const* d_in, const int* in_sizes, int n_in,
                              void* d_out, int out_size, void* d_ws, size_t ws_size,
                              hipStream_t stream) {
    const int*   ids   = (const int*)d_in[0];
    const float* te    = (const float*)d_in[1];
    const float* W     = (const float*)d_in[2];
    const float* bias  = (const float*)d_in[3];
    const float* Pr    = (const float*)d_in[4];
    const float* Pi    = (const float*)d_in[5];
    const float* oproj = (const float*)d_in[6];
    float* out = (float*)d_out;

    float*          h  = (float*)d_ws;                  // 65,536 f32
    unsigned short* hh = (unsigned short*)(h + 65536);  // 65,536
    unsigned short* ct = hh + 65536;                    // 131,072
    unsigned short* st = ct + 131072;                   // 131,072

    rinrec_k<<<256, 256, 0, stream>>>(ids, te, h, hh);

    for (int l = 0; l < 2; ++l) {
        theta_k<<<512, 512, 0, stream>>>(
            hh, W + (size_t)l * 524288, bias + l * 1024, ct, st);
        pv_k<<<256, 1024, 0, stream>>>(
            ct, st, Pr + (size_t)l * 524288, Pi + (size_t)l * 524288, h, hh);
    }

    logits_k<<<512, 512, 0, stream>>>(hh, oproj, out);
}